// Round 1
// baseline (660.943 us; speedup 1.0000x reference)
//
#include <hip/hip_runtime.h>
#include <cmath>

// Problem constants (from reference setup_inputs)
constexpr int B = 16, T = 2048, D = 2048, C = 100;
#define EPS_F 1e-7f

// ---------------------------------------------------------------------------
// Kernel 1: column sum over T for feat tensors.
// out[b*D+d] += sum_{t in chunk} feat[b,t,d].  float4 vectorized over d.
// grid = (D/1024, T/rows_per_chunk, B), block = 256
// ---------------------------------------------------------------------------
__global__ void colsum_kernel(const float* __restrict__ feat, float* __restrict__ out,
                              int rows_per_chunk) {
    const int b = blockIdx.z;
    const int d0 = (blockIdx.x * blockDim.x + threadIdx.x) * 4;
    const int t0 = blockIdx.y * rows_per_chunk;
    float4 acc = make_float4(0.f, 0.f, 0.f, 0.f);
    const float* base = feat + ((size_t)b * T + t0) * D + d0;
    for (int t = 0; t < rows_per_chunk; ++t) {
        float4 v = *reinterpret_cast<const float4*>(base + (size_t)t * D);
        acc.x += v.x; acc.y += v.y; acc.z += v.z; acc.w += v.w;
    }
    float* o = out + b * D + d0;
    atomicAdd(o + 0, acc.x);
    atomicAdd(o + 1, acc.y);
    atomicAdd(o + 2, acc.z);
    atomicAdd(o + 3, acc.w);
}

// ---------------------------------------------------------------------------
// Kernel 2: per-(b,c) stats for loss_sup.
// thread c (0..99 active of 128) accumulates over a t-chunk:
//   sumsq[b,c] += (sup - (gt>0.5))^2 ; cnt[b,c] += (gt>0.5)
// grid = (T/rows_per_chunk, B), block = 128
// ---------------------------------------------------------------------------
__global__ void sup_kernel(const float* __restrict__ gt, const float* __restrict__ sup,
                           float* __restrict__ sumsq, float* __restrict__ cnt,
                           int rows_per_chunk) {
    const int b = blockIdx.y;
    const int c = threadIdx.x;
    const int t0 = blockIdx.x * rows_per_chunk;
    if (c >= C) return;
    float acc = 0.f, pc = 0.f;
    size_t base = ((size_t)b * T + t0) * C + c;
    for (int t = 0; t < rows_per_chunk; ++t) {
        float g = gt[base + (size_t)t * C];
        float s = sup[base + (size_t)t * C];
        float m = (g > 0.5f) ? 1.f : 0.f;
        float d = s - m;
        acc += d * d;
        pc += m;
    }
    atomicAdd(&sumsq[b * C + c], acc);
    atomicAdd(&cnt[b * C + c], pc);
}

// ---------------------------------------------------------------------------
// Kernel 3: sum of squared differences (cas_s - cas_t)^2 over all elements.
// float4 grid-stride; one atomicAdd per block.
// ---------------------------------------------------------------------------
__global__ void st_kernel(const float4* __restrict__ s, const float4* __restrict__ t,
                          float* __restrict__ acc, int n4) {
    int idx = blockIdx.x * blockDim.x + threadIdx.x;
    int stride = gridDim.x * blockDim.x;
    float local = 0.f;
    for (int i = idx; i < n4; i += stride) {
        float4 a = s[i], b4 = t[i];
        float dx = a.x - b4.x, dy = a.y - b4.y, dz = a.z - b4.z, dw = a.w - b4.w;
        local += dx * dx + dy * dy + dz * dz + dw * dw;
    }
    // wave (64-lane) reduce
    for (int off = 32; off; off >>= 1) local += __shfl_down(local, off, 64);
    __shared__ float wsum[4];
    int lane = threadIdx.x & 63, wv = threadIdx.x >> 6;
    if (lane == 0) wsum[wv] = local;
    __syncthreads();
    if (threadIdx.x == 0) {
        atomicAdd(acc, wsum[0] + wsum[1] + wsum[2] + wsum[3]);
    }
}

// ---------------------------------------------------------------------------
// Kernel 4: final single-block finishing: BCEs, norms, sup, st, outputs.
// block = 256
// ---------------------------------------------------------------------------
__device__ __forceinline__ float block_reduce256(float v, float* sdata) {
    int tid = threadIdx.x;
    sdata[tid] = v;
    __syncthreads();
    for (int s = 128; s > 0; s >>= 1) {
        if (tid < s) sdata[tid] += sdata[tid + s];
        __syncthreads();
    }
    float r = sdata[0];
    __syncthreads();
    return r;
}

__global__ void final_kernel(const float* __restrict__ score_act,
                             const float* __restrict__ score_bkg,
                             const float* __restrict__ label,
                             const float* __restrict__ colsum_act,
                             const float* __restrict__ colsum_bkg,
                             const float* __restrict__ sup_sumsq,
                             const float* __restrict__ sup_cnt,
                             const float* __restrict__ st_acc,
                             float* __restrict__ out) {
    __shared__ float sdata[256];
    __shared__ float rowsum[B];
    __shared__ float an[B], bn[B];
    const int tid = threadIdx.x;
    const int N = B * C;

    // label row sums
    if (tid < B) rowsum[tid] = 0.f;
    __syncthreads();
    for (int i = tid; i < N; i += 256) atomicAdd(&rowsum[i / C], label[i]);
    __syncthreads();

    // loss_cls: BCE(score_act, label / rowsum)
    float lc = 0.f;
    for (int i = tid; i < N; i += 256) {
        float tgt = label[i] / rowsum[i / C];
        float p = fminf(fmaxf(score_act[i], EPS_F), 1.f - EPS_F);
        lc -= tgt * logf(p) + (1.f - tgt) * log1pf(-p);
    }
    float loss_cls = block_reduce256(lc, sdata) / (float)N;

    // loss_be: BCE(score_bkg, 1/C)
    float lb = 0.f;
    const float u = 1.f / (float)C;
    for (int i = tid; i < N; i += 256) {
        float p = fminf(fmaxf(score_bkg[i], EPS_F), 1.f - EPS_F);
        lb -= u * logf(p) + (1.f - u) * log1pf(-p);
    }
    float loss_be = block_reduce256(lb, sdata) / (float)N;

    // norms of mean features
    const float invT = 1.f / (float)T;
    for (int b = 0; b < B; ++b) {
        float la = 0.f, lg = 0.f;
        for (int d = tid; d < D; d += 256) {
            float va = colsum_act[b * D + d] * invT;
            float vb = colsum_bkg[b * D + d] * invT;
            la += va * va;
            lg += vb * vb;
        }
        float sa = block_reduce256(la, sdata);
        float sb = block_reduce256(lg, sdata);
        if (tid == 0) { an[b] = sqrtf(sa); bn[b] = sqrtf(sb); }
    }
    __syncthreads();

    // loss_sup
    float ss = 0.f, sc = 0.f;
    for (int i = tid; i < N; i += 256) {
        if (sup_cnt[i] > 0.f) { ss += sqrtf(sup_sumsq[i]); sc += 1.f; }
    }
    float sup_sum = block_reduce256(ss, sdata);
    float sup_count = block_reduce256(sc, sdata);

    if (tid == 0) {
        float loss_um = 0.f;
        for (int b = 0; b < B; ++b) {
            float la = fmaxf(100.f - an[b], 0.f);
            float v = la + bn[b];
            loss_um += v * v;
        }
        loss_um /= (float)B;
        float loss_sup = sup_sum / fmaxf(sup_count, 1.f);
        float loss_st = *st_acc / (float)((size_t)B * T * C);
        float total = loss_cls + 0.0005f * loss_um + 1.0f * loss_be
                    + 1.0f * loss_sup + 1.0f * loss_st;
        out[0] = total;
        out[1] = loss_cls;
        out[2] = loss_be;
        out[3] = loss_um;
        out[4] = loss_sup;
        out[5] = loss_st;
    }
}

// ---------------------------------------------------------------------------
extern "C" void kernel_launch(void* const* d_in, const int* in_sizes, int n_in,
                              void* d_out, int out_size, void* d_ws, size_t ws_size,
                              hipStream_t stream) {
    const float* score_act = (const float*)d_in[0];
    const float* score_bkg = (const float*)d_in[1];
    const float* feat_act  = (const float*)d_in[2];
    const float* feat_bkg  = (const float*)d_in[3];
    const float* label     = (const float*)d_in[4];
    const float* gt        = (const float*)d_in[5];
    const float* sup_cas   = (const float*)d_in[6];
    const float* cas_s     = (const float*)d_in[7];
    const float* cas_t     = (const float*)d_in[8];
    float* out = (float*)d_out;
    float* ws  = (float*)d_ws;

    // workspace layout (floats): colsum_act[B*D] | colsum_bkg[B*D] |
    //                            sup_sumsq[B*C]  | sup_cnt[B*C]    | st_acc[1]
    float* colsum_act = ws;
    float* colsum_bkg = ws + (size_t)B * D;
    float* sup_sumsq  = ws + (size_t)2 * B * D;
    float* sup_cnt    = sup_sumsq + B * C;
    float* st_acc     = sup_cnt + B * C;
    size_t ws_needed  = ((size_t)2 * B * D + 2 * B * C + 1) * sizeof(float);

    // ws is re-poisoned to 0xAA before every timed launch — zero what we use.
    hipMemsetAsync(d_ws, 0, ws_needed, stream);

    {
        const int rows = 64;                       // 32 t-chunks
        dim3 grid(D / (256 * 4), T / rows, B);     // (2, 32, 16) = 1024 blocks/tensor
        colsum_kernel<<<grid, 256, 0, stream>>>(feat_act, colsum_act, rows);
        colsum_kernel<<<grid, 256, 0, stream>>>(feat_bkg, colsum_bkg, rows);
    }
    {
        const int rows = 32;
        dim3 grid(T / rows, B);                    // (64, 16) = 1024 blocks
        sup_kernel<<<grid, 128, 0, stream>>>(gt, sup_cas, sup_sumsq, sup_cnt, rows);
    }
    {
        int n4 = (B * T * C) / 4;                  // 819200, C divisible by 4
        st_kernel<<<1024, 256, 0, stream>>>((const float4*)cas_s, (const float4*)cas_t,
                                            st_acc, n4);
    }
    final_kernel<<<1, 256, 0, stream>>>(score_act, score_bkg, label,
                                        colsum_act, colsum_bkg,
                                        sup_sumsq, sup_cnt, st_acc, out);
}